// Round 1
// baseline (682.570 us; speedup 1.0000x reference)
//
#include <hip/hip_runtime.h>
#include <hip/hip_bf16.h>
#include <math.h>

// ---------------------------------------------------------------------------
// GAT edge classifier: emb GEMM -> 3x (GEMM + edge-softmax + aggregate) ->
// decomposed edge scorer. CSR (by dst) built on-device each call.
// ---------------------------------------------------------------------------

constexpr float SLOPE = 0.2f;

// ------------------------- GEMM: Y = X[N,128] @ W[128,M] (+bias) -----------
template<int M>
__global__ __launch_bounds__(512)
void gemm_k128(const float* __restrict__ X, const float* __restrict__ W,
               const float* __restrict__ bias, float* __restrict__ Y, int N) {
  constexpr int K = 128;
  constexpr int BM = 64;
  constexpr int CPT = M / 32;              // cols per thread: 4 (M=128) or 2 (M=64)
  __shared__ __align__(16) float Xs[BM][K];     // 32 KB
  __shared__ __align__(16) float Ws[K][M];      // 64 KB (M=128) / 32 KB (M=64)

  const int tid = threadIdx.x;
  const int row0 = blockIdx.x * BM;

  // stage X tile (BM*K floats = 2048 float4, 512 threads -> 4 each)
  #pragma unroll
  for (int j = 0; j < (BM * K) / (512 * 4); ++j) {
    int lin = tid + j * 512;               // float4 index
    int r = lin >> 5;                      // 32 float4 per row
    int c4 = lin & 31;
    int gr = row0 + r;
    float4 v = make_float4(0.f, 0.f, 0.f, 0.f);
    if (gr < N) v = reinterpret_cast<const float4*>(X + (size_t)gr * K)[c4];
    reinterpret_cast<float4*>(&Xs[r][0])[c4] = v;
  }
  // stage W (K*M floats)
  #pragma unroll
  for (int j = 0; j < (K * M) / (512 * 4); ++j) {
    int lin = tid + j * 512;
    reinterpret_cast<float4*>(&Ws[0][0])[lin] =
        reinterpret_cast<const float4*>(W)[lin];
  }
  __syncthreads();

  const int tr = tid >> 5;                 // 0..15 -> 4 rows each
  const int tc = tid & 31;                 // 0..31 -> CPT cols each

  float acc[4][CPT];
  #pragma unroll
  for (int i = 0; i < 4; ++i)
    #pragma unroll
    for (int c = 0; c < CPT; ++c) acc[i][c] = 0.f;

  #pragma unroll 8
  for (int k = 0; k < K; ++k) {
    float xv[4];
    #pragma unroll
    for (int i = 0; i < 4; ++i) xv[i] = Xs[tr * 4 + i][k];
    #pragma unroll
    for (int c = 0; c < CPT; ++c) {
      float wv = Ws[k][tc * CPT + c];
      #pragma unroll
      for (int i = 0; i < 4; ++i) acc[i][c] += xv[i] * wv;
    }
  }

  float bv[CPT];
  #pragma unroll
  for (int c = 0; c < CPT; ++c) bv[c] = bias ? bias[tc * CPT + c] : 0.f;

  #pragma unroll
  for (int i = 0; i < 4; ++i) {
    int gr = row0 + tr * 4 + i;
    if (gr < N) {
      if constexpr (CPT == 4) {
        float4 o = make_float4(acc[i][0] + bv[0], acc[i][1] + bv[1],
                               acc[i][2] + bv[2], acc[i][3] + bv[3]);
        *reinterpret_cast<float4*>(&Y[(size_t)gr * M + tc * 4]) = o;
      } else {
        float2 o = make_float2(acc[i][0] + bv[0], acc[i][1] + bv[1]);
        *reinterpret_cast<float2*>(&Y[(size_t)gr * M + tc * 2]) = o;
      }
    }
  }
}

// --------------------- per-(node,head) attention coefficients ---------------
__global__ void node_attn_coef(const float* __restrict__ feat,
                               const float* __restrict__ al,
                               const float* __restrict__ ar,
                               float* __restrict__ el, float* __restrict__ er,
                               int N, int H) {
  int gt = blockIdx.x * blockDim.x + threadIdx.x;
  int wid = gt >> 6;
  int lane = threadIdx.x & 63;
  if (wid >= N * H) return;
  int h = wid - (wid / H) * H;
  float f = feat[(size_t)wid * 64 + lane];
  float a = f * al[h * 64 + lane];
  float b = f * ar[h * 64 + lane];
  #pragma unroll
  for (int off = 32; off; off >>= 1) {
    a += __shfl_xor(a, off);
    b += __shfl_xor(b, off);
  }
  if (lane == 0) { el[wid] = a; er[wid] = b; }
}

// ------------------------------ CSR build ----------------------------------
__global__ void count_dst(const int* __restrict__ dst, int* __restrict__ cnt,
                          int E) {
  int i = blockIdx.x * blockDim.x + threadIdx.x;
  if (i < E) atomicAdd(&cnt[dst[i]], 1);
}

__global__ void scan1(const int* __restrict__ cnt, int* __restrict__ outv,
                      int* __restrict__ bsum, int n) {
  __shared__ int sm[256];
  int tid = threadIdx.x;
  int base = blockIdx.x * 1024 + tid * 4;
  int pre[4];
  int s = 0;
  #pragma unroll
  for (int j = 0; j < 4; ++j) {
    int idx = base + j;
    int v = (idx < n) ? cnt[idx] : 0;
    pre[j] = s;
    s += v;
  }
  sm[tid] = s;
  __syncthreads();
  for (int off = 1; off < 256; off <<= 1) {
    int a = (tid >= off) ? sm[tid - off] : 0;
    __syncthreads();
    sm[tid] += a;
    __syncthreads();
  }
  int excl = sm[tid] - s;
  #pragma unroll
  for (int j = 0; j < 4; ++j) {
    int idx = base + j;
    if (idx < n) outv[idx] = excl + pre[j];
  }
  if (tid == 255) bsum[blockIdx.x] = sm[255];
}

__global__ void scan2(const int* __restrict__ bsum, int* __restrict__ btop,
                      int nb, int* __restrict__ row_last) {
  if (threadIdx.x == 0 && blockIdx.x == 0) {
    int s = 0;
    for (int i = 0; i < nb; ++i) { btop[i] = s; s += bsum[i]; }
    *row_last = s;   // row_ptr[N] = E
  }
}

__global__ void scan3(int* __restrict__ rp, int* __restrict__ cur,
                      const int* __restrict__ btop, int n) {
  int i = blockIdx.x * blockDim.x + threadIdx.x;
  if (i < n) {
    int v = rp[i] + btop[i >> 10];
    rp[i] = v;
    cur[i] = v;
  }
}

__global__ void scatter_edges(const int* __restrict__ dst,
                              int* __restrict__ cur, int* __restrict__ eidx,
                              int E) {
  int i = blockIdx.x * blockDim.x + threadIdx.x;
  if (i < E) {
    int p = atomicAdd(&cur[dst[i]], 1);
    eidx[p] = i;
  }
}

// ---------------- fused edge-softmax + aggregation + bias + elu -------------
// one 64-lane wave per (node, head); lane == feature dim d
__global__ void gat_aggregate(const float* __restrict__ feat,
                              const float* __restrict__ el,
                              const float* __restrict__ er,
                              const float* __restrict__ bias,
                              const int* __restrict__ row_ptr,
                              const int* __restrict__ eidx,
                              const int* __restrict__ src,
                              float* __restrict__ hout, int N, int H) {
  int gt = blockIdx.x * blockDim.x + threadIdx.x;
  int wid = gt >> 6;
  int lane = threadIdx.x & 63;
  if (wid >= N * H) return;
  int node = wid / H;
  int head = wid - node * H;
  int beg = row_ptr[node];
  int end = row_ptr[node + 1];
  float ern = er[wid];

  float acc = 0.f;
  float denom = 0.f;
  for (int p = beg; p < end; p += 64) {
    int m = end - p;
    if (m > 64) m = 64;
    float ex = 0.f;
    int s = 0;
    if (lane < m) {
      int e = eidx[p + lane];
      s = src[e];
      float ev = el[s * H + head] + ern;
      ev = ev > 0.f ? ev : SLOPE * ev;
      ex = expf(ev);
    }
    for (int j = 0; j < m; ++j) {
      float exj = __shfl(ex, j);
      int sj = __shfl(s, j);
      denom += exj;
      acc += exj * feat[(size_t)sj * (H * 64) + head * 64 + lane];
    }
  }
  float r = acc / (denom > 0.f ? denom : 1.f) + bias[head * 64 + lane];
  hout[(size_t)wid * 64 + lane] = r > 0.f ? r : expm1f(r);
}

// ----------------------- decomposed edge scorer ----------------------------
__global__ void score_partial(const float* __restrict__ h3,
                              const float* __restrict__ Ws,
                              float* __restrict__ ps, float* __restrict__ pd,
                              int N) {
  int gt = blockIdx.x * blockDim.x + threadIdx.x;
  int n = gt >> 6;
  int lane = threadIdx.x & 63;
  if (n >= N) return;
  float v = h3[(size_t)n * 64 + lane];
  float a0 = v * Ws[lane * 2 + 0];
  float a1 = v * Ws[lane * 2 + 1];
  float a2 = v * Ws[(64 + lane) * 2 + 0];
  float a3 = v * Ws[(64 + lane) * 2 + 1];
  #pragma unroll
  for (int off = 32; off; off >>= 1) {
    a0 += __shfl_xor(a0, off);
    a1 += __shfl_xor(a1, off);
    a2 += __shfl_xor(a2, off);
    a3 += __shfl_xor(a3, off);
  }
  if (lane == 0) {
    ps[n * 2 + 0] = a0;
    ps[n * 2 + 1] = a1;
    pd[n * 2 + 0] = a2;
    pd[n * 2 + 1] = a3;
  }
}

__global__ void score_out(const int* __restrict__ src,
                          const int* __restrict__ dst,
                          const float* __restrict__ ps,
                          const float* __restrict__ pd,
                          const float* __restrict__ bs,
                          float* __restrict__ out, int E) {
  int i = blockIdx.x * blockDim.x + threadIdx.x;
  if (i < E) {
    int s = src[i], d = dst[i];
    float2 a = *reinterpret_cast<const float2*>(ps + (size_t)s * 2);
    float2 b = *reinterpret_cast<const float2*>(pd + (size_t)d * 2);
    float2 o;
    o.x = a.x + b.x + bs[0];
    o.y = a.y + b.y + bs[1];
    *reinterpret_cast<float2*>(out + (size_t)i * 2) = o;
  }
}

// ---------------------------------------------------------------------------
extern "C" void kernel_launch(void* const* d_in, const int* in_sizes, int n_in,
                              void* d_out, int out_size, void* d_ws,
                              size_t ws_size, hipStream_t stream) {
  const float* x    = (const float*)d_in[0];
  const int*   src  = (const int*)d_in[1];
  const int*   dst  = (const int*)d_in[2];
  const float* Wemb = (const float*)d_in[3];
  const float* bemb = (const float*)d_in[4];
  const float* W0   = (const float*)d_in[5];
  const float* al0  = (const float*)d_in[6];
  const float* ar0  = (const float*)d_in[7];
  const float* b0   = (const float*)d_in[8];
  const float* W1   = (const float*)d_in[9];
  const float* al1  = (const float*)d_in[10];
  const float* ar1  = (const float*)d_in[11];
  const float* b1   = (const float*)d_in[12];
  const float* W2   = (const float*)d_in[13];
  const float* al2  = (const float*)d_in[14];
  const float* ar2  = (const float*)d_in[15];
  const float* b2   = (const float*)d_in[16];
  const float* Wsc  = (const float*)d_in[17];
  const float* bsc  = (const float*)d_in[18];

  const int N = in_sizes[0] / 128;
  const int E = in_sizes[1];
  float* out = (float*)d_out;

  // workspace carve-up
  char* w = (char*)d_ws;
  float* A   = (float*)w; w += (size_t)N * 128 * 4;   // h_in / h_out ping
  float* B   = (float*)w; w += (size_t)N * 128 * 4;   // feat
  float* el  = (float*)w; w += (size_t)N * 2 * 4;
  float* er  = (float*)w; w += (size_t)N * 2 * 4;
  float* ps  = (float*)w; w += (size_t)N * 2 * 4;
  float* pd  = (float*)w; w += (size_t)N * 2 * 4;
  int* cnt   = (int*)w;   w += (size_t)N * 4;
  int* rp    = (int*)w;   w += (size_t)(N + 1) * 4;
  int* cur   = (int*)w;   w += (size_t)N * 4;
  int* eidx  = (int*)w;   w += (size_t)E * 4;
  int* bsum  = (int*)w;   w += 4096;
  int* btop  = (int*)w;   w += 4096;

  // ---- CSR build (by dst) ----
  hipMemsetAsync(cnt, 0, (size_t)N * 4, stream);
  count_dst<<<(E + 255) / 256, 256, 0, stream>>>(dst, cnt, E);
  int nb = (N + 1023) / 1024;
  scan1<<<nb, 256, 0, stream>>>(cnt, rp, bsum, N);
  scan2<<<1, 64, 0, stream>>>(bsum, btop, nb, rp + N);
  scan3<<<(N + 255) / 256, 256, 0, stream>>>(rp, cur, btop, N);
  scatter_edges<<<(E + 255) / 256, 256, 0, stream>>>(dst, cur, eidx, E);

  const int gb = (N + 63) / 64;
  const int nt2 = N * 2 * 64;   // threads for H=2 per-(node,head) kernels
  const int nt1 = N * 1 * 64;

  // ---- embedding ----
  gemm_k128<128><<<gb, 512, 0, stream>>>(x, Wemb, bemb, A, N);

  // ---- GAT layer 0 (2 heads x 64) ----
  gemm_k128<128><<<gb, 512, 0, stream>>>(A, W0, nullptr, B, N);
  node_attn_coef<<<(nt2 + 255) / 256, 256, 0, stream>>>(B, al0, ar0, el, er, N, 2);
  gat_aggregate<<<(nt2 + 255) / 256, 256, 0, stream>>>(B, el, er, b0, rp, eidx,
                                                       src, A, N, 2);
  // ---- GAT layer 1 ----
  gemm_k128<128><<<gb, 512, 0, stream>>>(A, W1, nullptr, B, N);
  node_attn_coef<<<(nt2 + 255) / 256, 256, 0, stream>>>(B, al1, ar1, el, er, N, 2);
  gat_aggregate<<<(nt2 + 255) / 256, 256, 0, stream>>>(B, el, er, b1, rp, eidx,
                                                       src, A, N, 2);
  // ---- GAT layer 2 (1 head x 64) ----
  gemm_k128<64><<<gb, 512, 0, stream>>>(A, W2, nullptr, B, N);
  node_attn_coef<<<(nt1 + 255) / 256, 256, 0, stream>>>(B, al2, ar2, el, er, N, 1);
  gat_aggregate<<<(nt1 + 255) / 256, 256, 0, stream>>>(B, el, er, b2, rp, eidx,
                                                       src, A, N, 1);

  // ---- edge scorer: out[e] = P_src[src[e]] + P_dst[dst[e]] + bs ----
  score_partial<<<(nt1 + 255) / 256, 256, 0, stream>>>(A, Wsc, ps, pd, N);
  score_out<<<(E + 255) / 256, 256, 0, stream>>>(src, dst, ps, pd, bsc, out, E);
}

// Round 3
// 527.548 us; speedup vs baseline: 1.2939x; 1.2939x over previous
//
#include <hip/hip_runtime.h>
#include <hip/hip_bf16.h>
#include <math.h>

// ---------------------------------------------------------------------------
// GAT edge classifier: emb GEMM -> 3x (GEMM[+el/er epilogue] + edge_prep +
// aggregate) -> decomposed edge scorer. CSR (by dst) built on-device per call.
// ---------------------------------------------------------------------------

constexpr float SLOPE = 0.2f;

// ---------- GEMM: Y = X[N,128] @ W[128,M] (+bias) [+ el/er epilogue] -------
template<int M>
__global__ __launch_bounds__(512)
void gemm_k128(const float* __restrict__ X, const float* __restrict__ W,
               const float* __restrict__ bias,
               const float* __restrict__ al, const float* __restrict__ ar,
               float* __restrict__ Y, float* __restrict__ el,
               float* __restrict__ er, int N) {
  constexpr int K = 128;
  constexpr int BM = 64;
  constexpr int CPT = M / 32;              // 4 (M=128) or 2 (M=64)
  constexpr int H = M / 64;
  __shared__ __align__(16) float Xs[BM][K];
  __shared__ __align__(16) float Wsm[K][M];

  const int tid = threadIdx.x;
  const int row0 = blockIdx.x * BM;

  #pragma unroll
  for (int j = 0; j < (BM * K) / (512 * 4); ++j) {
    int lin = tid + j * 512;
    int r = lin >> 5;
    int c4 = lin & 31;
    int gr = row0 + r;
    float4 v = make_float4(0.f, 0.f, 0.f, 0.f);
    if (gr < N) v = reinterpret_cast<const float4*>(X + (size_t)gr * K)[c4];
    reinterpret_cast<float4*>(&Xs[r][0])[c4] = v;
  }
  #pragma unroll
  for (int j = 0; j < (K * M) / (512 * 4); ++j) {
    int lin = tid + j * 512;
    reinterpret_cast<float4*>(&Wsm[0][0])[lin] =
        reinterpret_cast<const float4*>(W)[lin];
  }
  __syncthreads();

  const int tr = tid >> 5;                 // 16 row-groups of 4 rows
  const int tc = tid & 31;                 // 32 col-groups of CPT cols

  float acc[4][CPT];
  #pragma unroll
  for (int i = 0; i < 4; ++i)
    #pragma unroll
    for (int c = 0; c < CPT; ++c) acc[i][c] = 0.f;

  #pragma unroll 8
  for (int k = 0; k < K; ++k) {
    float xv[4];
    #pragma unroll
    for (int i = 0; i < 4; ++i) xv[i] = Xs[tr * 4 + i][k];
    #pragma unroll
    for (int c = 0; c < CPT; ++c) {
      float wv = Wsm[k][tc * CPT + c];
      #pragma unroll
      for (int i = 0; i < 4; ++i) acc[i][c] += xv[i] * wv;
    }
  }

  float bv[CPT];
  #pragma unroll
  for (int c = 0; c < CPT; ++c) bv[c] = bias ? bias[tc * CPT + c] : 0.f;

  #pragma unroll
  for (int i = 0; i < 4; ++i) {
    int gr = row0 + tr * 4 + i;
    if (gr < N) {
      if constexpr (CPT == 4) {
        float4 o = make_float4(acc[i][0] + bv[0], acc[i][1] + bv[1],
                               acc[i][2] + bv[2], acc[i][3] + bv[3]);
        *reinterpret_cast<float4*>(&Y[(size_t)gr * M + tc * 4]) = o;
      } else {
        float2 o = make_float2(acc[i][0] + bv[0], acc[i][1] + bv[1]);
        *reinterpret_cast<float2*>(&Y[(size_t)gr * M + tc * 2]) = o;
      }
    }
  }

  // ---- fused attention-coefficient epilogue: el/er = feat . al/ar ----
  if (al != nullptr) {
    int head, colbase;
    if constexpr (CPT == 4) { head = tc >> 4; colbase = tc * 4 - head * 64; }
    else                    { head = 0;       colbase = tc * 2; }
    float av[CPT], rv[CPT];
    #pragma unroll
    for (int c = 0; c < CPT; ++c) {
      av[c] = al[head * 64 + colbase + c];
      rv[c] = ar[head * 64 + colbase + c];
    }
    #pragma unroll
    for (int i = 0; i < 4; ++i) {
      float pl = 0.f, pr = 0.f;
      #pragma unroll
      for (int c = 0; c < CPT; ++c) {
        pl += acc[i][c] * av[c];
        pr += acc[i][c] * rv[c];
      }
      if constexpr (CPT == 4) {
        #pragma unroll
        for (int off = 1; off < 16; off <<= 1) {
          pl += __shfl_xor(pl, off);
          pr += __shfl_xor(pr, off);
        }
        if ((tc & 15) == 0) {
          int gr = row0 + tr * 4 + i;
          if (gr < N) { el[gr * H + head] = pl; er[gr * H + head] = pr; }
        }
      } else {
        #pragma unroll
        for (int off = 1; off < 32; off <<= 1) {
          pl += __shfl_xor(pl, off);
          pr += __shfl_xor(pr, off);
        }
        if (tc == 0) {
          int gr = row0 + tr * 4 + i;
          if (gr < N) { el[gr] = pl; er[gr] = pr; }
        }
      }
    }
  }
}

// ------------------------------ CSR build ----------------------------------
__global__ void count_dst(const int* __restrict__ dst, int* __restrict__ cnt,
                          int E) {
  int i = blockIdx.x * blockDim.x + threadIdx.x;
  if (i < E) atomicAdd(&cnt[dst[i]], 1);
}

__global__ void scan1(const int* __restrict__ cnt, int* __restrict__ outv,
                      int* __restrict__ bsum, int n) {
  __shared__ int sm[256];
  int tid = threadIdx.x;
  int base = blockIdx.x * 1024 + tid * 4;
  int pre[4];
  int s = 0;
  #pragma unroll
  for (int j = 0; j < 4; ++j) {
    int idx = base + j;
    int v = (idx < n) ? cnt[idx] : 0;
    pre[j] = s;
    s += v;
  }
  sm[tid] = s;
  __syncthreads();
  for (int off = 1; off < 256; off <<= 1) {
    int a = (tid >= off) ? sm[tid - off] : 0;
    __syncthreads();
    sm[tid] += a;
    __syncthreads();
  }
  int excl = sm[tid] - s;
  #pragma unroll
  for (int j = 0; j < 4; ++j) {
    int idx = base + j;
    if (idx < n) outv[idx] = excl + pre[j];
  }
  if (tid == 255) bsum[blockIdx.x] = sm[255];
}

__global__ void scan2(const int* __restrict__ bsum, int* __restrict__ btop,
                      int nb, int* __restrict__ row_last) {
  if (threadIdx.x == 0 && blockIdx.x == 0) {
    int s = 0;
    for (int i = 0; i < nb; ++i) { btop[i] = s; s += bsum[i]; }
    *row_last = s;
  }
}

__global__ void scan3(int* __restrict__ rp, int* __restrict__ cur,
                      const int* __restrict__ btop, int n) {
  int i = blockIdx.x * blockDim.x + threadIdx.x;
  if (i < n) {
    int v = rp[i] + btop[i >> 10];
    rp[i] = v;
    cur[i] = v;
  }
}

__global__ void scatter_edges(const int* __restrict__ src,
                              const int* __restrict__ dst,
                              int* __restrict__ cur,
                              int* __restrict__ s_csr,
                              int* __restrict__ d_csr, int E) {
  int i = blockIdx.x * blockDim.x + threadIdx.x;
  if (i < E) {
    int d = dst[i];
    int p = atomicAdd(&cur[d], 1);
    s_csr[p] = src[i];
    d_csr[p] = d;
  }
}

// ---- per-edge (CSR order) softmax numerators: ex_csr[h*E + p] -------------
template<int H>
__global__ void edge_prep(const int* __restrict__ s_csr,
                          const int* __restrict__ d_csr,
                          const float* __restrict__ el,
                          const float* __restrict__ er,
                          float* __restrict__ ex_csr, int E) {
  int i = blockIdx.x * blockDim.x + threadIdx.x;
  if (i >= E) return;
  int s = s_csr[i];
  int d = d_csr[i];
  #pragma unroll
  for (int h = 0; h < H; ++h) {
    float ev = el[s * H + h] + er[d * H + h];
    ev = ev > 0.f ? ev : SLOPE * ev;
    ex_csr[(size_t)h * E + i] = __expf(ev);
  }
}

// ---------------- fused edge-softmax aggregation + bias + elu ---------------
// one 64-lane wave per (node, head); lane = (grp 0..3) x (float4 slot 0..15)
// each inner iteration gathers 16 edges via 4 independent 1KB load instrs
template<int H>
__global__ void gat_aggregate(const float* __restrict__ feat,
                              const float* __restrict__ ex_csr,
                              const int* __restrict__ s_csr,
                              const float* __restrict__ bias,
                              const int* __restrict__ row_ptr,
                              float* __restrict__ hout, int N, int E) {
  int gt = blockIdx.x * blockDim.x + threadIdx.x;
  int wid = gt >> 6;
  int lane = threadIdx.x & 63;
  if (wid >= N * H) return;
  int node = wid / H;
  int head = wid - node * H;
  int beg = row_ptr[node];
  int end = row_ptr[node + 1];
  const int grp = lane >> 4;
  const int sl = lane & 15;

  const float4* feat4 = reinterpret_cast<const float4*>(feat);
  const int rowoff = head * 16 + sl;       // within feat4 row (stride H*16)
  const float* exh = ex_csr + (size_t)head * E;

  float4 acc = make_float4(0.f, 0.f, 0.f, 0.f);
  float den = 0.f;

  for (int p = beg; p < end; p += 64) {
    int m = end - p;
    if (m > 64) m = 64;
    float exv = 0.f;
    int sv = 0;
    if (lane < m) {
      sv = s_csr[p + lane];
      exv = exh[p + lane];
    }
    den += exv;
    for (int jj = 0; jj < m; jj += 16) {
      int ib = jj + grp;                   // <= 63 always (jj <= 48)
      float e0 = __shfl(exv, ib);
      float e1 = __shfl(exv, ib + 4);
      float e2 = __shfl(exv, ib + 8);
      float e3 = __shfl(exv, ib + 12);
      int s0 = __shfl(sv, ib);
      int s1 = __shfl(sv, ib + 4);
      int s2 = __shfl(sv, ib + 8);
      int s3 = __shfl(sv, ib + 12);
      float4 v0 = feat4[(size_t)s0 * (H * 16) + rowoff];
      float4 v1 = feat4[(size_t)s1 * (H * 16) + rowoff];
      float4 v2 = feat4[(size_t)s2 * (H * 16) + rowoff];
      float4 v3 = feat4[(size_t)s3 * (H * 16) + rowoff];
      acc.x += e0 * v0.x; acc.y += e0 * v0.y; acc.z += e0 * v0.z; acc.w += e0 * v0.w;
      acc.x += e1 * v1.x; acc.y += e1 * v1.y; acc.z += e1 * v1.z; acc.w += e1 * v1.w;
      acc.x += e2 * v2.x; acc.y += e2 * v2.y; acc.z += e2 * v2.z; acc.w += e2 * v2.w;
      acc.x += e3 * v3.x; acc.y += e3 * v3.y; acc.z += e3 * v3.z; acc.w += e3 * v3.w;
    }
  }

  // reduce partial acc across the 4 groups (lanes sl, sl+16, sl+32, sl+48)
  acc.x += __shfl_xor(acc.x, 16); acc.x += __shfl_xor(acc.x, 32);
  acc.y += __shfl_xor(acc.y, 16); acc.y += __shfl_xor(acc.y, 32);
  acc.z += __shfl_xor(acc.z, 16); acc.z += __shfl_xor(acc.z, 32);
  acc.w += __shfl_xor(acc.w, 16); acc.w += __shfl_xor(acc.w, 32);
  // reduce denom across all 64 lanes
  #pragma unroll
  for (int off = 1; off < 64; off <<= 1) den += __shfl_xor(den, off);

  if (lane < 16) {
    float inv = 1.f / (den > 0.f ? den : 1.f);
    float4 bv = reinterpret_cast<const float4*>(bias)[head * 16 + sl];
    float4 r;
    r.x = acc.x * inv + bv.x;
    r.y = acc.y * inv + bv.y;
    r.z = acc.z * inv + bv.z;
    r.w = acc.w * inv + bv.w;
    r.x = r.x > 0.f ? r.x : expm1f(r.x);
    r.y = r.y > 0.f ? r.y : expm1f(r.y);
    r.z = r.z > 0.f ? r.z : expm1f(r.z);
    r.w = r.w > 0.f ? r.w : expm1f(r.w);
    reinterpret_cast<float4*>(hout)[(size_t)wid * 16 + sl] = r;
  }
}

// ----------------------- decomposed edge scorer ----------------------------
__global__ void score_partial(const float* __restrict__ h3,
                              const float* __restrict__ Ws,
                              float* __restrict__ ps, float* __restrict__ pd,
                              int N) {
  int gt = blockIdx.x * blockDim.x + threadIdx.x;
  int n = gt >> 6;
  int lane = threadIdx.x & 63;
  if (n >= N) return;
  float v = h3[(size_t)n * 64 + lane];
  float a0 = v * Ws[lane * 2 + 0];
  float a1 = v * Ws[lane * 2 + 1];
  float a2 = v * Ws[(64 + lane) * 2 + 0];
  float a3 = v * Ws[(64 + lane) * 2 + 1];
  #pragma unroll
  for (int off = 32; off; off >>= 1) {
    a0 += __shfl_xor(a0, off);
    a1 += __shfl_xor(a1, off);
    a2 += __shfl_xor(a2, off);
    a3 += __shfl_xor(a3, off);
  }
  if (lane == 0) {
    ps[n * 2 + 0] = a0;
    ps[n * 2 + 1] = a1;
    pd[n * 2 + 0] = a2;
    pd[n * 2 + 1] = a3;
  }
}

__global__ void score_out(const int* __restrict__ src,
                          const int* __restrict__ dst,
                          const float* __restrict__ ps,
                          const float* __restrict__ pd,
                          const float* __restrict__ bs,
                          float* __restrict__ out, int E) {
  int i = blockIdx.x * blockDim.x + threadIdx.x;
  if (i < E) {
    int s = src[i], d = dst[i];
    float2 a = *reinterpret_cast<const float2*>(ps + (size_t)s * 2);
    float2 b = *reinterpret_cast<const float2*>(pd + (size_t)d * 2);
    float2 o;
    o.x = a.x + b.x + bs[0];
    o.y = a.y + b.y + bs[1];
    *reinterpret_cast<float2*>(out + (size_t)i * 2) = o;
  }
}

// ---------------------------------------------------------------------------
extern "C" void kernel_launch(void* const* d_in, const int* in_sizes, int n_in,
                              void* d_out, int out_size, void* d_ws,
                              size_t ws_size, hipStream_t stream) {
  const float* x    = (const float*)d_in[0];
  const int*   src  = (const int*)d_in[1];
  const int*   dst  = (const int*)d_in[2];
  const float* Wemb = (const float*)d_in[3];
  const float* bemb = (const float*)d_in[4];
  const float* W0   = (const float*)d_in[5];
  const float* al0  = (const float*)d_in[6];
  const float* ar0  = (const float*)d_in[7];
  const float* b0   = (const float*)d_in[8];
  const float* W1   = (const float*)d_in[9];
  const float* al1  = (const float*)d_in[10];
  const float* ar1  = (const float*)d_in[11];
  const float* b1   = (const float*)d_in[12];
  const float* W2   = (const float*)d_in[13];
  const float* al2  = (const float*)d_in[14];
  const float* ar2  = (const float*)d_in[15];
  const float* b2   = (const float*)d_in[16];
  const float* Wsc  = (const float*)d_in[17];
  const float* bsc  = (const float*)d_in[18];

  const int N = in_sizes[0] / 128;
  const int E = in_sizes[1];
  float* out = (float*)d_out;

  // workspace carve-up (float4-accessed buffers first, all 16B-aligned)
  char* w = (char*)d_ws;
  float* A      = (float*)w; w += (size_t)N * 128 * 4;   // h ping
  float* B      = (float*)w; w += (size_t)N * 128 * 4;   // feat
  float* ex_csr = (float*)w; w += (size_t)E * 2 * 4;     // per-head planes
  float* el  = (float*)w; w += (size_t)N * 2 * 4;
  float* er  = (float*)w; w += (size_t)N * 2 * 4;
  float* ps  = (float*)w; w += (size_t)N * 2 * 4;
  float* pd  = (float*)w; w += (size_t)N * 2 * 4;
  int* s_csr = (int*)w;   w += (size_t)E * 4;
  int* d_csr = (int*)w;   w += (size_t)E * 4;
  int* cnt   = (int*)w;   w += (size_t)N * 4;
  int* rp    = (int*)w;   w += (size_t)(N + 4) * 4;
  int* cur   = (int*)w;   w += (size_t)N * 4;
  int* bsum  = (int*)w;   w += 4096;
  int* btop  = (int*)w;   w += 4096;

  // ---- CSR build (by dst) ----
  hipMemsetAsync(cnt, 0, (size_t)N * 4, stream);
  count_dst<<<(E + 255) / 256, 256, 0, stream>>>(dst, cnt, E);
  int nb = (N + 1023) / 1024;
  scan1<<<nb, 256, 0, stream>>>(cnt, rp, bsum, N);
  scan2<<<1, 64, 0, stream>>>(bsum, btop, nb, rp + N);
  scan3<<<(N + 255) / 256, 256, 0, stream>>>(rp, cur, btop, N);
  scatter_edges<<<(E + 255) / 256, 256, 0, stream>>>(src, dst, cur, s_csr,
                                                     d_csr, E);

  const int gb = (N + 63) / 64;
  const int eb = (E + 255) / 256;
  const int nt2 = N * 2 * 64;
  const int nt1 = N * 1 * 64;

  // ---- embedding ----
  gemm_k128<128><<<gb, 512, 0, stream>>>(x, Wemb, bemb, nullptr, nullptr,
                                         A, nullptr, nullptr, N);

  // ---- GAT layer 0 ----
  gemm_k128<128><<<gb, 512, 0, stream>>>(A, W0, nullptr, al0, ar0, B, el, er, N);
  edge_prep<2><<<eb, 256, 0, stream>>>(s_csr, d_csr, el, er, ex_csr, E);
  gat_aggregate<2><<<(nt2 + 255) / 256, 256, 0, stream>>>(B, ex_csr, s_csr, b0,
                                                          rp, A, N, E);
  // ---- GAT layer 1 ----
  gemm_k128<128><<<gb, 512, 0, stream>>>(A, W1, nullptr, al1, ar1, B, el, er, N);
  edge_prep<2><<<eb, 256, 0, stream>>>(s_csr, d_csr, el, er, ex_csr, E);
  gat_aggregate<2><<<(nt2 + 255) / 256, 256, 0, stream>>>(B, ex_csr, s_csr, b1,
                                                          rp, A, N, E);
  // ---- GAT layer 2 (1 head) ----
  gemm_k128<64><<<gb, 512, 0, stream>>>(A, W2, nullptr, al2, ar2, B, el, er, N);
  edge_prep<1><<<eb, 256, 0, stream>>>(s_csr, d_csr, el, er, ex_csr, E);
  gat_aggregate<1><<<(nt1 + 255) / 256, 256, 0, stream>>>(B, ex_csr, s_csr, b2,
                                                          rp, A, N, E);

  // ---- edge scorer ----
  score_partial<<<(nt1 + 255) / 256, 256, 0, stream>>>(A, Wsc, ps, pd, N);
  score_out<<<(E + 255) / 256, 256, 0, stream>>>(src, dst, ps, pd, bsc, out, E);
}